// Round 3
// baseline (311.522 us; speedup 1.0000x reference)
//
#include <hip/hip_runtime.h>
#include <hip/hip_bf16.h>
#include <math.h>

// Problem constants
#define NB    2048          // B
#define ACT   14
#define NC    128           // C
#define NH    32            // H
#define NNODE (NB*ACT)      // 28672
#define NEDGE (NB*ACT*ACT)  // 401408
#define NPAIR (NB*ACT*ACT)  // 401408 output rows (b, 196)

// ---------------------------------------------------------------------------
// tiled fp32 GEMM, A [nrows x 128] @ W [128 x ncols] -> C [nrows x ncols]
// 64x64 tile, 256 threads, 4x4 register blocking, XOR-swizzled A tile in LDS.
// Optional per-row output scale (rowscale != nullptr -> C[r,:] *= rowscale[r]).
// ---------------------------------------------------------------------------
__global__ __launch_bounds__(256) void gemm_k128(
    const float* __restrict__ A, const float* __restrict__ W,
    float* __restrict__ C, int ncols, const float* __restrict__ rowscale)
{
    __shared__ float As[64 * 128];   // 32 KB
    __shared__ float Ws[128 * 64];   // 32 KB
    const int tid  = threadIdx.x;
    const int row0 = blockIdx.x * 64;
    const int col0 = blockIdx.y * 64;

    {
        const float4* Ag = (const float4*)(A + (size_t)row0 * 128);
#pragma unroll
        for (int it = 0; it < 8; ++it) {
            int idx = tid + it * 256;          // float4 index in tile
            int r = idx >> 5;
            int c = (idx & 31) << 2;           // float col, multiple of 4
            int cs = c ^ (((r >> 2) & 3) << 2);
            *((float4*)&As[r * 128 + cs]) = Ag[r * 32 + (c >> 2)];
        }
#pragma unroll
        for (int it = 0; it < 8; ++it) {
            int idx = tid + it * 256;
            int k = idx >> 4;
            int c = (idx & 15) << 2;
            *((float4*)&Ws[k * 64 + c]) =
                *((const float4*)&W[(size_t)k * ncols + col0 + c]);
        }
    }
    __syncthreads();

    const int tx = tid & 15;       // col group
    const int ty = tid >> 4;       // row group
    const int ri0 = ty * 4;

    float acc[4][4] = {};
    for (int k = 0; k < 128; k += 4) {
        float a_s[4][4];
        float w_s[4][4];
#pragma unroll
        for (int i = 0; i < 4; ++i) {
            int r = ri0 + i;
            *((float4*)&a_s[i][0]) =
                *((const float4*)&As[r * 128 + (k ^ (((r >> 2) & 3) << 2))]);
        }
#pragma unroll
        for (int kk = 0; kk < 4; ++kk) {
            *((float4*)&w_s[kk][0]) =
                *((const float4*)&Ws[(k + kk) * 64 + tx * 4]);
        }
#pragma unroll
        for (int kk = 0; kk < 4; ++kk)
#pragma unroll
            for (int i = 0; i < 4; ++i)
#pragma unroll
                for (int j = 0; j < 4; ++j)
                    acc[i][j] += a_s[i][kk] * w_s[kk][j];
    }

#pragma unroll
    for (int i = 0; i < 4; ++i) {
        float s = rowscale ? rowscale[row0 + ri0 + i] : 1.0f;
        float4 v = make_float4(acc[i][0] * s, acc[i][1] * s,
                               acc[i][2] * s, acc[i][3] * s);
        *((float4*)&C[(size_t)(row0 + ri0 + i) * ncols + col0 + tx * 4]) = v;
    }
}

// ---------------------------------------------------------------------------
// pack W1 [256x32] -> Wp [128x64]  (cols 0..31 = W1[k], cols 32..63 = W1[128+k])
// ---------------------------------------------------------------------------
__global__ void pack_w1(const float* __restrict__ W1, float* __restrict__ Wp)
{
    int idx = blockIdx.x * blockDim.x + threadIdx.x;   // 0..8191
    if (idx >= 128 * 64) return;
    int k = idx >> 6, c = idx & 63;
    Wp[idx] = (c < 32) ? W1[k * 32 + c] : W1[(128 + k) * 32 + (c - 32)];
}

// ---------------------------------------------------------------------------
// degree histogram (int atomics)
// ---------------------------------------------------------------------------
__global__ void deg_count(const int* __restrict__ dst, int* __restrict__ deg)
{
    int e = blockIdx.x * blockDim.x + threadIdx.x;
    if (e < NEDGE) atomicAdd(&deg[dst[e]], 1);
}

// ---------------------------------------------------------------------------
// single-block exclusive scan of deg -> cursor (start offsets); also dinv.
// 28672 = 1024 threads x 28 elements each.
// ---------------------------------------------------------------------------
__global__ __launch_bounds__(1024) void scan_dinv(
    const int* __restrict__ deg, int* __restrict__ cursor,
    float* __restrict__ dinv)
{
    __shared__ int part[1024];
    const int t = threadIdx.x;
    const int base = t * 28;
    int local[28];
    int s = 0;
#pragma unroll
    for (int i = 0; i < 28; ++i) { local[i] = s; s += deg[base + i]; }
    part[t] = s;
    __syncthreads();
    int own = s;
    for (int off = 1; off < 1024; off <<= 1) {
        int tmp = (t >= off) ? part[t - off] : 0;
        __syncthreads();
        part[t] += tmp;
        __syncthreads();
    }
    int prefix = part[t] - own;   // exclusive prefix of this thread's chunk
#pragma unroll
    for (int i = 0; i < 28; ++i) {
        cursor[base + i] = prefix + local[i];
        dinv[base + i] = rsqrtf((float)deg[base + i] + 1.0f);
    }
}

// ---------------------------------------------------------------------------
// CSR fill: csr_src[pos] = src[e], pos = cursor[dst[e]]++  (int atomics)
// After this kernel cursor[d] == end offset of node d.
// ---------------------------------------------------------------------------
__global__ void csr_fill(const int* __restrict__ src, const int* __restrict__ dst,
                         int* __restrict__ cursor, int* __restrict__ csr_src)
{
    int e = blockIdx.x * blockDim.x + threadIdx.x;
    if (e < NEDGE) {
        int pos = atomicAdd(&cursor[dst[e]], 1);
        csr_src[pos] = src[e];
    }
}

// ---------------------------------------------------------------------------
// gather aggregation + GCN epilogue, fused:
//   x[d] = relu(dinv[d] * (y[d] + sum_{e->d} y[src]) + bias) + state[d]
// One 32-lane group per node; lane q owns channels [4q, 4q+4).
// Inactive lanes point at dummy zero row NNODE; inner loop unrolled 4-wide
// so 4 gathers are in flight.
// ---------------------------------------------------------------------------
__global__ __launch_bounds__(256) void gather_agg(
    const int* __restrict__ csr_src, const int* __restrict__ cursor,
    const int* __restrict__ deg, const float* __restrict__ y,
    const float* __restrict__ dinv, const float* __restrict__ bias,
    const float* __restrict__ state, float* __restrict__ xout)
{
    const int lane = threadIdx.x & 31;
    const int d = (blockIdx.x * 256 + threadIdx.x) >> 5;   // node id
    if (d >= NNODE) return;

    const int cnt = deg[d];
    const int end = cursor[d];
    const int start = end - cnt;

    float4 acc = ((const float4*)(y + (size_t)d * NC))[lane];  // self loop
    for (int base = 0; base < cnt; base += 32) {
        int rem = cnt - base;
        int m = rem < 32 ? rem : 32;
        int sv = (lane < m) ? csr_src[start + base + lane] : NNODE; // zero row
        int mm = (m + 3) & ~3;
        for (int j = 0; j < mm; j += 4) {
            int s0 = __shfl(sv, j + 0, 32);
            int s1 = __shfl(sv, j + 1, 32);
            int s2 = __shfl(sv, j + 2, 32);
            int s3 = __shfl(sv, j + 3, 32);
            float4 v0 = ((const float4*)(y + (size_t)s0 * NC))[lane];
            float4 v1 = ((const float4*)(y + (size_t)s1 * NC))[lane];
            float4 v2 = ((const float4*)(y + (size_t)s2 * NC))[lane];
            float4 v3 = ((const float4*)(y + (size_t)s3 * NC))[lane];
            acc.x += v0.x + v1.x + v2.x + v3.x;
            acc.y += v0.y + v1.y + v2.y + v3.y;
            acc.z += v0.z + v1.z + v2.z + v3.z;
            acc.w += v0.w + v1.w + v2.w + v3.w;
        }
    }

    const float dv = dinv[d];
    float4 b  = ((const float4*)bias)[lane];
    float4 st = ((const float4*)(state + (size_t)d * NC))[lane];
    float4 r;
    r.x = fmaxf(acc.x * dv + b.x, 0.f) + st.x;
    r.y = fmaxf(acc.y * dv + b.y, 0.f) + st.y;
    r.z = fmaxf(acc.z * dv + b.z, 0.f) + st.z;
    r.w = fmaxf(acc.w * dv + b.w, 0.f) + st.w;
    ((float4*)(xout + (size_t)d * NC))[lane] = r;
}

// ---------------------------------------------------------------------------
// pairs kernel, 2 pairs per thread.
// Pairs (2m, 2m+1) always share batch b AND row i (since 2m mod 14 is even,
// j <= 12), so u is loaded once and each W2 LDS read feeds 2x the FMAs.
// ---------------------------------------------------------------------------
__device__ __forceinline__ float softplusf(float z)
{
    return z > 0.f ? z + log1pf(expf(-z)) : log1pf(expf(z));
}

__global__ __launch_bounds__(256) void pairs2_kernel(
    const float* __restrict__ uv, const float* __restrict__ W2,
    const float* __restrict__ b1, const float* __restrict__ b2,
    const float* __restrict__ muW, const float* __restrict__ mu_b,
    const float* __restrict__ sigW, const float* __restrict__ sig_b,
    float* __restrict__ out)
{
    __shared__ float W2s[1024];
    __shared__ float b1s[32], b2s[32], muWs[32], sigWs[32];
    const int tid = threadIdx.x;
    for (int i = tid; i < 1024; i += 256) W2s[i] = W2[i];
    if (tid < 32) {
        b1s[tid] = b1[tid];
        b2s[tid] = b2[tid];
        muWs[tid] = muW[tid];
        sigWs[tid] = sigW[tid];
    }
    __syncthreads();

    int gid = blockIdx.x * 256 + tid;          // 0 .. NPAIR/2-1
    int b = gid / 98;                          // 2*gid / 196
    int r = 2 * gid - b * 196;                 // even, 0..194
    int i = r / 14;
    int j = r - i * 14;                        // even, <= 12

    const float* up  = uv + (size_t)(b * ACT + i) * 64;
    const float* vap = uv + (size_t)(b * ACT + j) * 64 + 32;
    const float* vbp = vap + 64;               // pair j+1

    float h1a[32], h1b[32];
#pragma unroll
    for (int k4 = 0; k4 < 8; ++k4) {
        float4 uu = ((const float4*)up)[k4];
        float4 va = ((const float4*)vap)[k4];
        float4 vb = ((const float4*)vbp)[k4];
        float bb0 = b1s[k4 * 4 + 0], bb1 = b1s[k4 * 4 + 1];
        float bb2 = b1s[k4 * 4 + 2], bb3 = b1s[k4 * 4 + 3];
        float za0 = uu.x + va.x + bb0, zb0 = uu.x + vb.x + bb0;
        float za1 = uu.y + va.y + bb1, zb1 = uu.y + vb.y + bb1;
        float za2 = uu.z + va.z + bb2, zb2 = uu.z + vb.z + bb2;
        float za3 = uu.w + va.w + bb3, zb3 = uu.w + vb.w + bb3;
        h1a[k4 * 4 + 0] = za0 > 0.f ? za0 : 0.01f * za0;
        h1a[k4 * 4 + 1] = za1 > 0.f ? za1 : 0.01f * za1;
        h1a[k4 * 4 + 2] = za2 > 0.f ? za2 : 0.01f * za2;
        h1a[k4 * 4 + 3] = za3 > 0.f ? za3 : 0.01f * za3;
        h1b[k4 * 4 + 0] = zb0 > 0.f ? zb0 : 0.01f * zb0;
        h1b[k4 * 4 + 1] = zb1 > 0.f ? zb1 : 0.01f * zb1;
        h1b[k4 * 4 + 2] = zb2 > 0.f ? zb2 : 0.01f * zb2;
        h1b[k4 * 4 + 3] = zb3 > 0.f ? zb3 : 0.01f * zb3;
    }

    float h2a[32], h2b[32];
#pragma unroll
    for (int l = 0; l < 32; ++l) { h2a[l] = b2s[l]; h2b[l] = b2s[l]; }
#pragma unroll
    for (int k = 0; k < 32; ++k) {
        float ka = h1a[k];
        float kb = h1b[k];
        const float4* wr = (const float4*)&W2s[k * 32];
#pragma unroll
        for (int l4 = 0; l4 < 8; ++l4) {
            float4 w = wr[l4];
            h2a[l4 * 4 + 0] += ka * w.x;  h2b[l4 * 4 + 0] += kb * w.x;
            h2a[l4 * 4 + 1] += ka * w.y;  h2b[l4 * 4 + 1] += kb * w.y;
            h2a[l4 * 4 + 2] += ka * w.z;  h2b[l4 * 4 + 2] += kb * w.z;
            h2a[l4 * 4 + 3] += ka * w.w;  h2b[l4 * 4 + 3] += kb * w.w;
        }
    }

    float mua = mu_b[0] + 1e-10f, mub = mua;
    float sga = sig_b[0],          sgb = sga;
#pragma unroll
    for (int l = 0; l < 32; ++l) {
        float mw = muWs[l], sw = sigWs[l];
        float ha = h2a[l];
        ha = ha > 0.f ? ha : 0.01f * ha;
        mua += ha * mw;  sga += ha * sw;
        float hb = h2b[l];
        hb = hb > 0.f ? hb : 0.01f * hb;
        mub += hb * mw;  sgb += hb * sw;
    }
    int p0 = 2 * gid;
    out[p0]             = softplusf(mua);
    out[p0 + 1]         = softplusf(mub);
    out[NPAIR + p0]     = expf(fminf(fmaxf(sga, -20.f), 2.f));
    out[NPAIR + p0 + 1] = expf(fminf(fmaxf(sgb, -20.f), 2.f));
}

// ---------------------------------------------------------------------------
// launch
// ---------------------------------------------------------------------------
extern "C" void kernel_launch(void* const* d_in, const int* in_sizes, int n_in,
                              void* d_out, int out_size, void* d_ws, size_t ws_size,
                              hipStream_t stream)
{
    const float* state  = (const float*)d_in[0];
    const float* conv_W = (const float*)d_in[1];
    const float* conv_b = (const float*)d_in[2];
    const float* lin1_W = (const float*)d_in[3];
    const float* lin1_b = (const float*)d_in[4];
    const float* lin2_W = (const float*)d_in[5];
    const float* lin2_b = (const float*)d_in[6];
    const float* mu_W   = (const float*)d_in[7];
    const float* mu_b   = (const float*)d_in[8];
    const float* sig_W  = (const float*)d_in[9];
    const float* sig_b  = (const float*)d_in[10];
    const int*   eidx   = (const int*)d_in[11];
    const int* e_src = eidx;
    const int* e_dst = eidx + NEDGE;

    float* out = (float*)d_out;

    // workspace layout (floats)
    float* ws = (float*)d_ws;
    float* y     = ws;                               // (N+1)*128; row N = zeros
    float* x     = y + (size_t)(NNODE + 1) * 128;    // N*128
    float* dinv  = x + (size_t)NNODE * 128;          // N
    int*   deg   = (int*)(dinv + NNODE);             // N
    int*   cursor= deg + NNODE;                      // N
    int*   csrs  = cursor + NNODE;                   // E
    float* Wp    = (float*)(csrs + NEDGE);           // 128*64
    float* uvb   = x + (size_t)NNODE * 64;           // reuse tail of x? NO:
    uvb = Wp + 128 * 64;                             // uv [N x 64], own region

    // zero the degree histogram + dummy y row (ws poisoned once, not re-poisoned)
    hipMemsetAsync(deg, 0, (size_t)NNODE * sizeof(int), stream);
    hipMemsetAsync(y + (size_t)NNODE * 128, 0, 128 * sizeof(float), stream);

    // CSR build
    deg_count<<<NEDGE / 256, 256, 0, stream>>>(e_dst, deg);
    scan_dinv<<<1, 1024, 0, stream>>>(deg, cursor, dinv);
    csr_fill<<<NEDGE / 256, 256, 0, stream>>>(e_src, e_dst, cursor, csrs);

    // pack W1
    pack_w1<<<32, 256, 0, stream>>>(lin1_W, Wp);

    // y = (state @ conv_W) * dinv[row]
    gemm_k128<<<dim3(NNODE / 64, 2), 256, 0, stream>>>(state, conv_W, y, 128, dinv);

    // x = relu(dinv*(y_self + sum y[src]) + b) + state
    gather_agg<<<(NNODE * 32) / 256, 256, 0, stream>>>(
        csrs, cursor, deg, y, dinv, conv_b, state, x);

    // uv = x @ [W1_top | W1_bot]
    gemm_k128<<<dim3(NNODE / 64, 1), 256, 0, stream>>>(x, Wp, uvb, 64, nullptr);

    // pairs -> output (2 pairs per thread)
    pairs2_kernel<<<NPAIR / 512, 256, 0, stream>>>(
        uvb, lin2_W, lin1_b, lin2_b, mu_W, mu_b, sig_W, sig_b, out);
}

// Round 4
// 168.065 us; speedup vs baseline: 1.8536x; 1.8536x over previous
//
#include <hip/hip_runtime.h>
#include <hip/hip_bf16.h>
#include <math.h>

// Problem constants
#define NB    2048          // B
#define ACT   14
#define NC    128           // C
#define NH    32            // H
#define NNODE (NB*ACT)      // 28672
#define NEDGE (NB*ACT*ACT)  // 401408
#define NPAIR (NB*ACT*ACT)  // 401408 output rows (b, 196)

// ---------------------------------------------------------------------------
// tiled fp32 GEMM, A [nrows x 128] @ W [128 x ncols] -> C [nrows x ncols]
// 64x64 tile, 256 threads, 4x4 register blocking, XOR-swizzled A tile in LDS.
// Optional per-row output scale (rowscale != nullptr -> C[r,:] *= rowscale[r]).
// ---------------------------------------------------------------------------
__global__ __launch_bounds__(256) void gemm_k128(
    const float* __restrict__ A, const float* __restrict__ W,
    float* __restrict__ C, int ncols, const float* __restrict__ rowscale)
{
    __shared__ float As[64 * 128];   // 32 KB
    __shared__ float Ws[128 * 64];   // 32 KB
    const int tid  = threadIdx.x;
    const int row0 = blockIdx.x * 64;
    const int col0 = blockIdx.y * 64;

    {
        const float4* Ag = (const float4*)(A + (size_t)row0 * 128);
#pragma unroll
        for (int it = 0; it < 8; ++it) {
            int idx = tid + it * 256;          // float4 index in tile
            int r = idx >> 5;
            int c = (idx & 31) << 2;           // float col, multiple of 4
            int cs = c ^ (((r >> 2) & 3) << 2);
            *((float4*)&As[r * 128 + cs]) = Ag[r * 32 + (c >> 2)];
        }
#pragma unroll
        for (int it = 0; it < 8; ++it) {
            int idx = tid + it * 256;
            int k = idx >> 4;
            int c = (idx & 15) << 2;
            *((float4*)&Ws[k * 64 + c]) =
                *((const float4*)&W[(size_t)k * ncols + col0 + c]);
        }
    }
    __syncthreads();

    const int tx = tid & 15;       // col group
    const int ty = tid >> 4;       // row group
    const int ri0 = ty * 4;

    float acc[4][4] = {};
    for (int k = 0; k < 128; k += 4) {
        float a_s[4][4];
        float w_s[4][4];
#pragma unroll
        for (int i = 0; i < 4; ++i) {
            int r = ri0 + i;
            *((float4*)&a_s[i][0]) =
                *((const float4*)&As[r * 128 + (k ^ (((r >> 2) & 3) << 2))]);
        }
#pragma unroll
        for (int kk = 0; kk < 4; ++kk) {
            *((float4*)&w_s[kk][0]) =
                *((const float4*)&Ws[(k + kk) * 64 + tx * 4]);
        }
#pragma unroll
        for (int kk = 0; kk < 4; ++kk)
#pragma unroll
            for (int i = 0; i < 4; ++i)
#pragma unroll
                for (int j = 0; j < 4; ++j)
                    acc[i][j] += a_s[i][kk] * w_s[kk][j];
    }

#pragma unroll
    for (int i = 0; i < 4; ++i) {
        float s = rowscale ? rowscale[row0 + ri0 + i] : 1.0f;
        float4 v = make_float4(acc[i][0] * s, acc[i][1] * s,
                               acc[i][2] * s, acc[i][3] * s);
        *((float4*)&C[(size_t)(row0 + ri0 + i) * ncols + col0 + tx * 4]) = v;
    }
}

// ---------------------------------------------------------------------------
// pack W1 [256x32] -> Wp [128x64]  (cols 0..31 = W1[k], cols 32..63 = W1[128+k])
// ---------------------------------------------------------------------------
__global__ void pack_w1(const float* __restrict__ W1, float* __restrict__ Wp)
{
    int idx = blockIdx.x * blockDim.x + threadIdx.x;   // 0..8191
    if (idx >= 128 * 64) return;
    int k = idx >> 6, c = idx & 63;
    Wp[idx] = (c < 32) ? W1[k * 32 + c] : W1[(128 + k) * 32 + (c - 32)];
}

// ---------------------------------------------------------------------------
// degree histogram (int atomics)
// ---------------------------------------------------------------------------
__global__ void deg_count(const int* __restrict__ dst, int* __restrict__ deg)
{
    int e = blockIdx.x * blockDim.x + threadIdx.x;
    if (e < NEDGE) atomicAdd(&deg[dst[e]], 1);
}

// ---------------------------------------------------------------------------
// single-block exclusive scan of deg -> cursor (start offsets); also dinv.
// 28672 = 1024 threads x 28 elements each.
// ---------------------------------------------------------------------------
__global__ __launch_bounds__(1024) void scan_dinv(
    const int* __restrict__ deg, int* __restrict__ cursor,
    float* __restrict__ dinv)
{
    __shared__ int part[1024];
    const int t = threadIdx.x;
    const int base = t * 28;
    int local[28];
    int s = 0;
#pragma unroll
    for (int i = 0; i < 28; ++i) { local[i] = s; s += deg[base + i]; }
    part[t] = s;
    __syncthreads();
    int own = s;
    for (int off = 1; off < 1024; off <<= 1) {
        int tmp = (t >= off) ? part[t - off] : 0;
        __syncthreads();
        part[t] += tmp;
        __syncthreads();
    }
    int prefix = part[t] - own;   // exclusive prefix of this thread's chunk
#pragma unroll
    for (int i = 0; i < 28; ++i) {
        cursor[base + i] = prefix + local[i];
        dinv[base + i] = rsqrtf((float)deg[base + i] + 1.0f);
    }
}

// ---------------------------------------------------------------------------
// CSR fill: csr_src[pos] = src[e], pos = cursor[dst[e]]++  (int atomics)
// After this kernel cursor[d] == end offset of node d.
// ---------------------------------------------------------------------------
__global__ void csr_fill(const int* __restrict__ src, const int* __restrict__ dst,
                         int* __restrict__ cursor, int* __restrict__ csr_src)
{
    int e = blockIdx.x * blockDim.x + threadIdx.x;
    if (e < NEDGE) {
        int pos = atomicAdd(&cursor[dst[e]], 1);
        csr_src[pos] = src[e];
    }
}

// ---------------------------------------------------------------------------
// gather aggregation + GCN epilogue, fused:
//   x[d] = relu(dinv[d] * (y[d] + sum_{e->d} y[src]) + bias) + state[d]
// One 32-lane group per node; lane q owns channels [4q, 4q+4).
// Inactive lanes point at dummy zero row NNODE; inner loop unrolled 4-wide.
// ---------------------------------------------------------------------------
__global__ __launch_bounds__(256) void gather_agg(
    const int* __restrict__ csr_src, const int* __restrict__ cursor,
    const int* __restrict__ deg, const float* __restrict__ y,
    const float* __restrict__ dinv, const float* __restrict__ bias,
    const float* __restrict__ state, float* __restrict__ xout)
{
    const int lane = threadIdx.x & 31;
    const int d = (blockIdx.x * 256 + threadIdx.x) >> 5;   // node id
    if (d >= NNODE) return;

    const int cnt = deg[d];
    const int end = cursor[d];
    const int start = end - cnt;

    float4 acc = ((const float4*)(y + (size_t)d * NC))[lane];  // self loop
    for (int base = 0; base < cnt; base += 32) {
        int rem = cnt - base;
        int m = rem < 32 ? rem : 32;
        int sv = (lane < m) ? csr_src[start + base + lane] : NNODE; // zero row
        int mm = (m + 3) & ~3;
        for (int j = 0; j < mm; j += 4) {
            int s0 = __shfl(sv, j + 0, 32);
            int s1 = __shfl(sv, j + 1, 32);
            int s2 = __shfl(sv, j + 2, 32);
            int s3 = __shfl(sv, j + 3, 32);
            float4 v0 = ((const float4*)(y + (size_t)s0 * NC))[lane];
            float4 v1 = ((const float4*)(y + (size_t)s1 * NC))[lane];
            float4 v2 = ((const float4*)(y + (size_t)s2 * NC))[lane];
            float4 v3 = ((const float4*)(y + (size_t)s3 * NC))[lane];
            acc.x += v0.x + v1.x + v2.x + v3.x;
            acc.y += v0.y + v1.y + v2.y + v3.y;
            acc.z += v0.z + v1.z + v2.z + v3.z;
            acc.w += v0.w + v1.w + v2.w + v3.w;
        }
    }

    const float dv = dinv[d];
    float4 b  = ((const float4*)bias)[lane];
    float4 st = ((const float4*)(state + (size_t)d * NC))[lane];
    float4 r;
    r.x = fmaxf(acc.x * dv + b.x, 0.f) + st.x;
    r.y = fmaxf(acc.y * dv + b.y, 0.f) + st.y;
    r.z = fmaxf(acc.z * dv + b.z, 0.f) + st.z;
    r.w = fmaxf(acc.w * dv + b.w, 0.f) + st.w;
    ((float4*)(xout + (size_t)d * NC))[lane] = r;
}

// ---------------------------------------------------------------------------
// pairs kernel: 2 pairs x 16 h2-columns per thread.
// Thread gid handles pairs (2m, 2m+1), m = gid>>1 (both share batch b and
// row i since 2m mod 14 is even), and h2 columns [c0, c0+16), c0=(gid&1)*16.
// h1 is folded into the k-loop (no 32-float h1 arrays -> no spills).
// Partner threads (lane^1) exchange partial mu/sig dots via shfl_xor.
// ---------------------------------------------------------------------------
__device__ __forceinline__ float softplusf(float z)
{
    return z > 0.f ? z + log1pf(expf(-z)) : log1pf(expf(z));
}

__global__ __launch_bounds__(256) void pairs_half_kernel(
    const float* __restrict__ uv, const float* __restrict__ W2,
    const float* __restrict__ b1, const float* __restrict__ b2,
    const float* __restrict__ muW, const float* __restrict__ mu_b,
    const float* __restrict__ sigW, const float* __restrict__ sig_b,
    float* __restrict__ out)
{
    __shared__ float W2s[1024];
    __shared__ float b1s[32], b2s[32], muWs[32], sigWs[32];
    const int tid = threadIdx.x;
    for (int i = tid; i < 1024; i += 256) W2s[i] = W2[i];
    if (tid < 32) {
        b1s[tid] = b1[tid];
        b2s[tid] = b2[tid];
        muWs[tid] = muW[tid];
        sigWs[tid] = sigW[tid];
    }
    __syncthreads();

    const int gid = blockIdx.x * 256 + tid;    // 0 .. NPAIR-1
    const int m = gid >> 1;                    // pair-group
    const int c0 = (gid & 1) << 4;             // 0 or 16: owned h2 columns
    const int b = m / 98;
    const int r = 2 * m - b * 196;             // even, 0..194
    const int i = r / 14;
    const int j = r - i * 14;                  // even, <= 12

    const float* up  = uv + (size_t)(b * ACT + i) * 64;
    const float* vap = uv + (size_t)(b * ACT + j) * 64 + 32;
    const float* vbp = vap + 64;               // pair j+1

    float h2a[16], h2b[16];
#pragma unroll
    for (int l = 0; l < 16; ++l) { h2a[l] = b2s[c0 + l]; h2b[l] = h2a[l]; }

#pragma unroll
    for (int k4 = 0; k4 < 8; ++k4) {
        float4 uu = ((const float4*)up)[k4];
        float4 va = ((const float4*)vap)[k4];
        float4 vb = ((const float4*)vbp)[k4];
        float h1a[4], h1b[4];
        {
            float z;
            z = uu.x + va.x + b1s[k4 * 4 + 0]; h1a[0] = z > 0.f ? z : 0.01f * z;
            z = uu.y + va.y + b1s[k4 * 4 + 1]; h1a[1] = z > 0.f ? z : 0.01f * z;
            z = uu.z + va.z + b1s[k4 * 4 + 2]; h1a[2] = z > 0.f ? z : 0.01f * z;
            z = uu.w + va.w + b1s[k4 * 4 + 3]; h1a[3] = z > 0.f ? z : 0.01f * z;
            z = uu.x + vb.x + b1s[k4 * 4 + 0]; h1b[0] = z > 0.f ? z : 0.01f * z;
            z = uu.y + vb.y + b1s[k4 * 4 + 1]; h1b[1] = z > 0.f ? z : 0.01f * z;
            z = uu.z + vb.z + b1s[k4 * 4 + 2]; h1b[2] = z > 0.f ? z : 0.01f * z;
            z = uu.w + vb.w + b1s[k4 * 4 + 3]; h1b[3] = z > 0.f ? z : 0.01f * z;
        }
#pragma unroll
        for (int kk = 0; kk < 4; ++kk) {
            float ka = h1a[kk];
            float kb = h1b[kk];
            const float4* wr = (const float4*)&W2s[(k4 * 4 + kk) * 32 + c0];
#pragma unroll
            for (int l4 = 0; l4 < 4; ++l4) {
                float4 w = wr[l4];
                h2a[l4 * 4 + 0] += ka * w.x;  h2b[l4 * 4 + 0] += kb * w.x;
                h2a[l4 * 4 + 1] += ka * w.y;  h2b[l4 * 4 + 1] += kb * w.y;
                h2a[l4 * 4 + 2] += ka * w.z;  h2b[l4 * 4 + 2] += kb * w.z;
                h2a[l4 * 4 + 3] += ka * w.w;  h2b[l4 * 4 + 3] += kb * w.w;
            }
        }
    }

    // partial heads over own 16 columns
    float mua = 0.f, sga = 0.f, mub = 0.f, sgb = 0.f;
#pragma unroll
    for (int l = 0; l < 16; ++l) {
        float mw = muWs[c0 + l], sw = sigWs[c0 + l];
        float ha = h2a[l];
        ha = ha > 0.f ? ha : 0.01f * ha;
        float hb = h2b[l];
        hb = hb > 0.f ? hb : 0.01f * hb;
        mua += ha * mw;  sga += ha * sw;
        mub += hb * mw;  sgb += hb * sw;
    }
    // combine halves with partner lane (lane^1)
    mua += __shfl_xor(mua, 1);
    mub += __shfl_xor(mub, 1);
    sga += __shfl_xor(sga, 1);
    sgb += __shfl_xor(sgb, 1);

    float mu_t = ((gid & 1) ? mub : mua) + mu_b[0] + 1e-10f;
    float sg_t = ((gid & 1) ? sgb : sga) + sig_b[0];
    out[gid]         = softplusf(mu_t);
    out[NPAIR + gid] = expf(fminf(fmaxf(sg_t, -20.f), 2.f));
}

// ---------------------------------------------------------------------------
// launch
// ---------------------------------------------------------------------------
extern "C" void kernel_launch(void* const* d_in, const int* in_sizes, int n_in,
                              void* d_out, int out_size, void* d_ws, size_t ws_size,
                              hipStream_t stream)
{
    const float* state  = (const float*)d_in[0];
    const float* conv_W = (const float*)d_in[1];
    const float* conv_b = (const float*)d_in[2];
    const float* lin1_W = (const float*)d_in[3];
    const float* lin1_b = (const float*)d_in[4];
    const float* lin2_W = (const float*)d_in[5];
    const float* lin2_b = (const float*)d_in[6];
    const float* mu_W   = (const float*)d_in[7];
    const float* mu_b   = (const float*)d_in[8];
    const float* sig_W  = (const float*)d_in[9];
    const float* sig_b  = (const float*)d_in[10];
    const int*   eidx   = (const int*)d_in[11];
    const int* e_src = eidx;
    const int* e_dst = eidx + NEDGE;

    float* out = (float*)d_out;

    // workspace layout (floats)
    float* ws = (float*)d_ws;
    float* y     = ws;                               // (N+1)*128; row N = zeros
    float* x     = y + (size_t)(NNODE + 1) * 128;    // N*128
    float* dinv  = x + (size_t)NNODE * 128;          // N
    int*   deg   = (int*)(dinv + NNODE);             // N
    int*   cursor= deg + NNODE;                      // N
    int*   csrs  = cursor + NNODE;                   // E
    float* Wp    = (float*)(csrs + NEDGE);           // 128*64
    float* uvb   = Wp + 128 * 64;                    // uv [N x 64]

    // zero the degree histogram + dummy y row (ws poisoned once, not re-poisoned)
    hipMemsetAsync(deg, 0, (size_t)NNODE * sizeof(int), stream);
    hipMemsetAsync(y + (size_t)NNODE * 128, 0, 128 * sizeof(float), stream);

    // CSR build
    deg_count<<<NEDGE / 256, 256, 0, stream>>>(e_dst, deg);
    scan_dinv<<<1, 1024, 0, stream>>>(deg, cursor, dinv);
    csr_fill<<<NEDGE / 256, 256, 0, stream>>>(e_src, e_dst, cursor, csrs);

    // pack W1
    pack_w1<<<32, 256, 0, stream>>>(lin1_W, Wp);

    // y = (state @ conv_W) * dinv[row]
    gemm_k128<<<dim3(NNODE / 64, 2), 256, 0, stream>>>(state, conv_W, y, 128, dinv);

    // x = relu(dinv*(y_self + sum y[src]) + b) + state
    gather_agg<<<(NNODE * 32) / 256, 256, 0, stream>>>(
        csrs, cursor, deg, y, dinv, conv_b, state, x);

    // uv = x @ [W1_top | W1_bot]
    gemm_k128<<<dim3(NNODE / 64, 1), 256, 0, stream>>>(x, Wp, uvb, 64, nullptr);

    // pairs -> output (2 pairs x 16 cols per thread)
    pairs_half_kernel<<<NPAIR / 256, 256, 0, stream>>>(
        uvb, lin2_W, lin1_b, lin2_b, mu_W, mu_b, sig_W, sig_b, out);
}

// Round 5
// 145.686 us; speedup vs baseline: 2.1383x; 1.1536x over previous
//
#include <hip/hip_runtime.h>
#include <hip/hip_bf16.h>
#include <math.h>

// Problem constants
#define NB    2048          // B
#define ACT   14
#define NC    128           // C
#define NH    32            // H
#define NNODE (NB*ACT)      // 28672
#define NEDGE (NB*ACT*ACT)  // 401408
#define NPAIR (NB*ACT*ACT)  // 401408 output rows (b, 196)

// ---------------------------------------------------------------------------
// tiled fp32 GEMM, A [nrows x 128] @ W [128 x ncols] -> C [nrows x ncols]
// 64x64 tile, 256 threads, 4x4 register blocking, XOR-swizzled A tile in LDS.
// Optional per-row output scale (rowscale != nullptr -> C[r,:] *= rowscale[r]).
// ---------------------------------------------------------------------------
__global__ __launch_bounds__(256) void gemm_k128(
    const float* __restrict__ A, const float* __restrict__ W,
    float* __restrict__ C, int ncols, const float* __restrict__ rowscale)
{
    __shared__ float As[64 * 128];   // 32 KB
    __shared__ float Ws[128 * 64];   // 32 KB
    const int tid  = threadIdx.x;
    const int row0 = blockIdx.x * 64;
    const int col0 = blockIdx.y * 64;

    {
        const float4* Ag = (const float4*)(A + (size_t)row0 * 128);
#pragma unroll
        for (int it = 0; it < 8; ++it) {
            int idx = tid + it * 256;          // float4 index in tile
            int r = idx >> 5;
            int c = (idx & 31) << 2;           // float col, multiple of 4
            int cs = c ^ (((r >> 2) & 3) << 2);
            *((float4*)&As[r * 128 + cs]) = Ag[r * 32 + (c >> 2)];
        }
#pragma unroll
        for (int it = 0; it < 8; ++it) {
            int idx = tid + it * 256;
            int k = idx >> 4;
            int c = (idx & 15) << 2;
            *((float4*)&Ws[k * 64 + c]) =
                *((const float4*)&W[(size_t)k * ncols + col0 + c]);
        }
    }
    __syncthreads();

    const int tx = tid & 15;       // col group
    const int ty = tid >> 4;       // row group
    const int ri0 = ty * 4;

    float acc[4][4] = {};
    for (int k = 0; k < 128; k += 4) {
        float a_s[4][4];
        float w_s[4][4];
#pragma unroll
        for (int i = 0; i < 4; ++i) {
            int r = ri0 + i;
            *((float4*)&a_s[i][0]) =
                *((const float4*)&As[r * 128 + (k ^ (((r >> 2) & 3) << 2))]);
        }
#pragma unroll
        for (int kk = 0; kk < 4; ++kk) {
            *((float4*)&w_s[kk][0]) =
                *((const float4*)&Ws[(k + kk) * 64 + tx * 4]);
        }
#pragma unroll
        for (int kk = 0; kk < 4; ++kk)
#pragma unroll
            for (int i = 0; i < 4; ++i)
#pragma unroll
                for (int j = 0; j < 4; ++j)
                    acc[i][j] += a_s[i][kk] * w_s[kk][j];
    }

#pragma unroll
    for (int i = 0; i < 4; ++i) {
        float s = rowscale ? rowscale[row0 + ri0 + i] : 1.0f;
        float4 v = make_float4(acc[i][0] * s, acc[i][1] * s,
                               acc[i][2] * s, acc[i][3] * s);
        *((float4*)&C[(size_t)(row0 + ri0 + i) * ncols + col0 + tx * 4]) = v;
    }
}

// ---------------------------------------------------------------------------
// pack W1 [256x32] -> Wp [128x64]  (cols 0..31 = W1[k], cols 32..63 = W1[128+k])
// ---------------------------------------------------------------------------
__global__ void pack_w1(const float* __restrict__ W1, float* __restrict__ Wp)
{
    int idx = blockIdx.x * blockDim.x + threadIdx.x;   // 0..8191
    if (idx >= 128 * 64) return;
    int k = idx >> 6, c = idx & 63;
    Wp[idx] = (c < 32) ? W1[k * 32 + c] : W1[(128 + k) * 32 + (c - 32)];
}

// ---------------------------------------------------------------------------
// degree histogram (int atomics)
// ---------------------------------------------------------------------------
__global__ void deg_count(const int* __restrict__ dst, int* __restrict__ deg)
{
    int e = blockIdx.x * blockDim.x + threadIdx.x;
    if (e < NEDGE) atomicAdd(&deg[dst[e]], 1);
}

// ---------------------------------------------------------------------------
// single-block exclusive scan of deg -> cursor (start offsets); also dinv.
// 28672 = 1024 threads x 28 elements each.
// ---------------------------------------------------------------------------
__global__ __launch_bounds__(1024) void scan_dinv(
    const int* __restrict__ deg, int* __restrict__ cursor,
    float* __restrict__ dinv)
{
    __shared__ int part[1024];
    const int t = threadIdx.x;
    const int base = t * 28;
    int local[28];
    int s = 0;
#pragma unroll
    for (int i = 0; i < 28; ++i) { local[i] = s; s += deg[base + i]; }
    part[t] = s;
    __syncthreads();
    int own = s;
    for (int off = 1; off < 1024; off <<= 1) {
        int tmp = (t >= off) ? part[t - off] : 0;
        __syncthreads();
        part[t] += tmp;
        __syncthreads();
    }
    int prefix = part[t] - own;   // exclusive prefix of this thread's chunk
#pragma unroll
    for (int i = 0; i < 28; ++i) {
        cursor[base + i] = prefix + local[i];
        dinv[base + i] = rsqrtf((float)deg[base + i] + 1.0f);
    }
}

// ---------------------------------------------------------------------------
// CSR fill: csr_src[pos] = src[e], pos = cursor[dst[e]]++  (int atomics)
// After this kernel cursor[d] == end offset of node d.
// ---------------------------------------------------------------------------
__global__ void csr_fill(const int* __restrict__ src, const int* __restrict__ dst,
                         int* __restrict__ cursor, int* __restrict__ csr_src)
{
    int e = blockIdx.x * blockDim.x + threadIdx.x;
    if (e < NEDGE) {
        int pos = atomicAdd(&cursor[dst[e]], 1);
        csr_src[pos] = src[e];
    }
}

// ---------------------------------------------------------------------------
// gather aggregation + GCN epilogue, fused:
//   x[d] = relu(dinv[d] * (y[d] + sum_{e->d} y[src]) + bias) + state[d]
// One 32-lane group per node; lane q owns channels [4q, 4q+4).
// Inactive lanes point at dummy zero row NNODE; inner loop unrolled 4-wide.
// ---------------------------------------------------------------------------
__global__ __launch_bounds__(256) void gather_agg(
    const int* __restrict__ csr_src, const int* __restrict__ cursor,
    const int* __restrict__ deg, const float* __restrict__ y,
    const float* __restrict__ dinv, const float* __restrict__ bias,
    const float* __restrict__ state, float* __restrict__ xout)
{
    const int lane = threadIdx.x & 31;
    const int d = (blockIdx.x * 256 + threadIdx.x) >> 5;   // node id
    if (d >= NNODE) return;

    const int cnt = deg[d];
    const int end = cursor[d];
    const int start = end - cnt;

    float4 acc = ((const float4*)(y + (size_t)d * NC))[lane];  // self loop
    for (int base = 0; base < cnt; base += 32) {
        int rem = cnt - base;
        int m = rem < 32 ? rem : 32;
        int sv = (lane < m) ? csr_src[start + base + lane] : NNODE; // zero row
        int mm = (m + 3) & ~3;
        for (int j = 0; j < mm; j += 4) {
            int s0 = __shfl(sv, j + 0, 32);
            int s1 = __shfl(sv, j + 1, 32);
            int s2 = __shfl(sv, j + 2, 32);
            int s3 = __shfl(sv, j + 3, 32);
            float4 v0 = ((const float4*)(y + (size_t)s0 * NC))[lane];
            float4 v1 = ((const float4*)(y + (size_t)s1 * NC))[lane];
            float4 v2 = ((const float4*)(y + (size_t)s2 * NC))[lane];
            float4 v3 = ((const float4*)(y + (size_t)s3 * NC))[lane];
            acc.x += v0.x + v1.x + v2.x + v3.x;
            acc.y += v0.y + v1.y + v2.y + v3.y;
            acc.z += v0.z + v1.z + v2.z + v3.z;
            acc.w += v0.w + v1.w + v2.w + v3.w;
        }
    }

    const float dv = dinv[d];
    float4 b  = ((const float4*)bias)[lane];
    float4 st = ((const float4*)(state + (size_t)d * NC))[lane];
    float4 r;
    r.x = fmaxf(acc.x * dv + b.x, 0.f) + st.x;
    r.y = fmaxf(acc.y * dv + b.y, 0.f) + st.y;
    r.z = fmaxf(acc.z * dv + b.z, 0.f) + st.z;
    r.w = fmaxf(acc.w * dv + b.w, 0.f) + st.w;
    ((float4*)(xout + (size_t)d * NC))[lane] = r;
}

// ---------------------------------------------------------------------------
// pairs kernel, scalar-pipe weights: 1 pair per thread, NO LDS.
// All weight/bias accesses use thread-uniform indices on const __restrict__
// pointers (kernel writes only `out`) -> backend promotes them to s_load and
// the inner loop is pure v_fma_f32 with an SGPR multiplier.
// h2[32] in registers; #pragma unroll 2 on the k4 loop caps VGPR pressure.
// ---------------------------------------------------------------------------
__device__ __forceinline__ float softplusf(float z)
{
    return z > 0.f ? z + log1pf(expf(-z)) : log1pf(expf(z));
}

__global__ __launch_bounds__(256) void pairs_sgpr_kernel(
    const float* __restrict__ uv, const float* __restrict__ W2,
    const float* __restrict__ b1, const float* __restrict__ b2,
    const float* __restrict__ muW, const float* __restrict__ mu_b,
    const float* __restrict__ sigW, const float* __restrict__ sig_b,
    float* __restrict__ out)
{
    const int gid = blockIdx.x * 256 + threadIdx.x;   // 0 .. NPAIR-1
    const int b = gid / 196;
    const int p = gid - b * 196;
    const int i = p / 14;
    const int j = p - i * 14;

    const float* up = uv + (size_t)(b * ACT + i) * 64;
    const float* vp = uv + (size_t)(b * ACT + j) * 64 + 32;

    float h2[32];
#pragma unroll
    for (int l = 0; l < 32; ++l) h2[l] = b2[l];       // uniform -> s_load

#pragma unroll 2
    for (int k4 = 0; k4 < 8; ++k4) {
        float4 uu = ((const float4*)up)[k4];
        float4 vv = ((const float4*)vp)[k4];
#pragma unroll
        for (int kk = 0; kk < 4; ++kk) {
            float uvk = (kk == 0) ? uu.x + vv.x :
                        (kk == 1) ? uu.y + vv.y :
                        (kk == 2) ? uu.z + vv.z : uu.w + vv.w;
            float z = uvk + b1[k4 * 4 + kk];          // b1 uniform -> sgpr
            float h1k = z > 0.f ? z : 0.01f * z;
            const float* wrow = W2 + (k4 * 4 + kk) * 32;
#pragma unroll
            for (int l = 0; l < 32; ++l)
                h2[l] += h1k * wrow[l];               // s_load + v_fma (sgpr src)
        }
    }

    float mu_acc = mu_b[0] + 1e-10f;
    float sg = sig_b[0];
#pragma unroll
    for (int l = 0; l < 32; ++l) {
        float h = h2[l];
        h = h > 0.f ? h : 0.01f * h;
        mu_acc += h * muW[l];
        sg += h * sigW[l];
    }
    out[gid]         = softplusf(mu_acc);
    out[NPAIR + gid] = expf(fminf(fmaxf(sg, -20.f), 2.f));
}

// ---------------------------------------------------------------------------
// launch
// ---------------------------------------------------------------------------
extern "C" void kernel_launch(void* const* d_in, const int* in_sizes, int n_in,
                              void* d_out, int out_size, void* d_ws, size_t ws_size,
                              hipStream_t stream)
{
    const float* state  = (const float*)d_in[0];
    const float* conv_W = (const float*)d_in[1];
    const float* conv_b = (const float*)d_in[2];
    const float* lin1_W = (const float*)d_in[3];
    const float* lin1_b = (const float*)d_in[4];
    const float* lin2_W = (const float*)d_in[5];
    const float* lin2_b = (const float*)d_in[6];
    const float* mu_W   = (const float*)d_in[7];
    const float* mu_b   = (const float*)d_in[8];
    const float* sig_W  = (const float*)d_in[9];
    const float* sig_b  = (const float*)d_in[10];
    const int*   eidx   = (const int*)d_in[11];
    const int* e_src = eidx;
    const int* e_dst = eidx + NEDGE;

    float* out = (float*)d_out;

    // workspace layout (floats)
    float* ws = (float*)d_ws;
    float* y     = ws;                               // (N+1)*128; row N = zeros
    float* x     = y + (size_t)(NNODE + 1) * 128;    // N*128
    float* dinv  = x + (size_t)NNODE * 128;          // N
    int*   deg   = (int*)(dinv + NNODE);             // N
    int*   cursor= deg + NNODE;                      // N
    int*   csrs  = cursor + NNODE;                   // E
    float* Wp    = (float*)(csrs + NEDGE);           // 128*64
    float* uvb   = Wp + 128 * 64;                    // uv [N x 64]

    // zero the degree histogram + dummy y row (ws poisoned once, not re-poisoned)
    hipMemsetAsync(deg, 0, (size_t)NNODE * sizeof(int), stream);
    hipMemsetAsync(y + (size_t)NNODE * 128, 0, 128 * sizeof(float), stream);

    // CSR build
    deg_count<<<NEDGE / 256, 256, 0, stream>>>(e_dst, deg);
    scan_dinv<<<1, 1024, 0, stream>>>(deg, cursor, dinv);
    csr_fill<<<NEDGE / 256, 256, 0, stream>>>(e_src, e_dst, cursor, csrs);

    // pack W1
    pack_w1<<<32, 256, 0, stream>>>(lin1_W, Wp);

    // y = (state @ conv_W) * dinv[row]
    gemm_k128<<<dim3(NNODE / 64, 2), 256, 0, stream>>>(state, conv_W, y, 128, dinv);

    // x = relu(dinv*(y_self + sum y[src]) + b) + state
    gather_agg<<<(NNODE * 32) / 256, 256, 0, stream>>>(
        csrs, cursor, deg, y, dinv, conv_b, state, x);

    // uv = x @ [W1_top | W1_bot]
    gemm_k128<<<dim3(NNODE / 64, 1), 256, 0, stream>>>(x, Wp, uvb, 64, nullptr);

    // pairs -> output (1 pair per thread, scalar-pipe weights)
    pairs_sgpr_kernel<<<NPAIR / 256, 256, 0, stream>>>(
        uvb, lin2_W, lin1_b, lin2_b, mu_W, mu_b, sig_W, sig_b, out);
}

// Round 6
// 142.051 us; speedup vs baseline: 2.1930x; 1.0256x over previous
//
#include <hip/hip_runtime.h>
#include <hip/hip_bf16.h>
#include <math.h>

// Problem constants
#define NB    2048          // B
#define ACT   14
#define NC    128           // C
#define NH    32            // H
#define NNODE (NB*ACT)      // 28672
#define NEDGE (NB*ACT*ACT)  // 401408
#define NPAIR (NB*ACT*ACT)  // 401408 output rows (b, 196)

// ---------------------------------------------------------------------------
// init kernel: zero deg histogram, zero dummy y row, pack W1 [256x32]->Wp[128x64]
// Replaces 2x hipMemsetAsync (runtime fillBufferAligned = ~42us each in-graph!)
// + pack_w1 with one ~3us dispatch.
// ---------------------------------------------------------------------------
__global__ __launch_bounds__(256) void init_misc(
    int* __restrict__ deg, float* __restrict__ ydummy,
    const float* __restrict__ W1, float* __restrict__ Wp)
{
    int idx = blockIdx.x * 256 + threadIdx.x;          // 0 .. 28671
    if (idx < NNODE) deg[idx] = 0;
    if (idx < 128) ydummy[idx] = 0.f;
    if (idx < 128 * 64) {
        int k = idx >> 6, c = idx & 63;
        Wp[idx] = (c < 32) ? W1[k * 32 + c] : W1[(128 + k) * 32 + (c - 32)];
    }
}

// ---------------------------------------------------------------------------
// tiled fp32 GEMM, A [nrows x 128] @ W [128 x ncols] -> C [nrows x ncols]
// 64x64 tile, 256 threads, 4x4 register blocking, XOR-swizzled A tile in LDS.
// Optional per-row output scale (rowscale != nullptr -> C[r,:] *= rowscale[r]).
// ---------------------------------------------------------------------------
__global__ __launch_bounds__(256) void gemm_k128(
    const float* __restrict__ A, const float* __restrict__ W,
    float* __restrict__ C, int ncols, const float* __restrict__ rowscale)
{
    __shared__ float As[64 * 128];   // 32 KB
    __shared__ float Ws[128 * 64];   // 32 KB
    const int tid  = threadIdx.x;
    const int row0 = blockIdx.x * 64;
    const int col0 = blockIdx.y * 64;

    {
        const float4* Ag = (const float4*)(A + (size_t)row0 * 128);
#pragma unroll
        for (int it = 0; it < 8; ++it) {
            int idx = tid + it * 256;          // float4 index in tile
            int r = idx >> 5;
            int c = (idx & 31) << 2;           // float col, multiple of 4
            int cs = c ^ (((r >> 2) & 3) << 2);
            *((float4*)&As[r * 128 + cs]) = Ag[r * 32 + (c >> 2)];
        }
#pragma unroll
        for (int it = 0; it < 8; ++it) {
            int idx = tid + it * 256;
            int k = idx >> 4;
            int c = (idx & 15) << 2;
            *((float4*)&Ws[k * 64 + c]) =
                *((const float4*)&W[(size_t)k * ncols + col0 + c]);
        }
    }
    __syncthreads();

    const int tx = tid & 15;       // col group
    const int ty = tid >> 4;       // row group
    const int ri0 = ty * 4;

    float acc[4][4] = {};
    for (int k = 0; k < 128; k += 4) {
        float a_s[4][4];
        float w_s[4][4];
#pragma unroll
        for (int i = 0; i < 4; ++i) {
            int r = ri0 + i;
            *((float4*)&a_s[i][0]) =
                *((const float4*)&As[r * 128 + (k ^ (((r >> 2) & 3) << 2))]);
        }
#pragma unroll
        for (int kk = 0; kk < 4; ++kk) {
            *((float4*)&w_s[kk][0]) =
                *((const float4*)&Ws[(k + kk) * 64 + tx * 4]);
        }
#pragma unroll
        for (int kk = 0; kk < 4; ++kk)
#pragma unroll
            for (int i = 0; i < 4; ++i)
#pragma unroll
                for (int j = 0; j < 4; ++j)
                    acc[i][j] += a_s[i][kk] * w_s[kk][j];
    }

#pragma unroll
    for (int i = 0; i < 4; ++i) {
        float s = rowscale ? rowscale[row0 + ri0 + i] : 1.0f;
        float4 v = make_float4(acc[i][0] * s, acc[i][1] * s,
                               acc[i][2] * s, acc[i][3] * s);
        *((float4*)&C[(size_t)(row0 + ri0 + i) * ncols + col0 + tx * 4]) = v;
    }
}

// ---------------------------------------------------------------------------
// degree histogram (int atomics)
// ---------------------------------------------------------------------------
__global__ void deg_count(const int* __restrict__ dst, int* __restrict__ deg)
{
    int e = blockIdx.x * blockDim.x + threadIdx.x;
    if (e < NEDGE) atomicAdd(&deg[dst[e]], 1);
}

// ---------------------------------------------------------------------------
// single-block exclusive scan of deg -> cursor (start offsets); also dinv.
// 28672 = 1024 threads x 28 elements each.
// ---------------------------------------------------------------------------
__global__ __launch_bounds__(1024) void scan_dinv(
    const int* __restrict__ deg, int* __restrict__ cursor,
    float* __restrict__ dinv)
{
    __shared__ int part[1024];
    const int t = threadIdx.x;
    const int base = t * 28;
    int local[28];
    int s = 0;
#pragma unroll
    for (int i = 0; i < 28; ++i) { local[i] = s; s += deg[base + i]; }
    part[t] = s;
    __syncthreads();
    int own = s;
    for (int off = 1; off < 1024; off <<= 1) {
        int tmp = (t >= off) ? part[t - off] : 0;
        __syncthreads();
        part[t] += tmp;
        __syncthreads();
    }
    int prefix = part[t] - own;   // exclusive prefix of this thread's chunk
#pragma unroll
    for (int i = 0; i < 28; ++i) {
        cursor[base + i] = prefix + local[i];
        dinv[base + i] = rsqrtf((float)deg[base + i] + 1.0f);
    }
}

// ---------------------------------------------------------------------------
// CSR fill: csr_src[pos] = src[e], pos = cursor[dst[e]]++  (int atomics)
// After this kernel cursor[d] == end offset of node d.
// ---------------------------------------------------------------------------
__global__ void csr_fill(const int* __restrict__ src, const int* __restrict__ dst,
                         int* __restrict__ cursor, int* __restrict__ csr_src)
{
    int e = blockIdx.x * blockDim.x + threadIdx.x;
    if (e < NEDGE) {
        int pos = atomicAdd(&cursor[dst[e]], 1);
        csr_src[pos] = src[e];
    }
}

// ---------------------------------------------------------------------------
// gather aggregation + GCN epilogue, fused:
//   x[d] = relu(dinv[d] * (y[d] + sum_{e->d} y[src]) + bias) + state[d]
// One 32-lane group per node; lane q owns channels [4q, 4q+4).
// Inactive lanes point at dummy zero row NNODE; inner loop unrolled 4-wide.
// ---------------------------------------------------------------------------
__global__ __launch_bounds__(256) void gather_agg(
    const int* __restrict__ csr_src, const int* __restrict__ cursor,
    const int* __restrict__ deg, const float* __restrict__ y,
    const float* __restrict__ dinv, const float* __restrict__ bias,
    const float* __restrict__ state, float* __restrict__ xout)
{
    const int lane = threadIdx.x & 31;
    const int d = (blockIdx.x * 256 + threadIdx.x) >> 5;   // node id
    if (d >= NNODE) return;

    const int cnt = deg[d];
    const int end = cursor[d];
    const int start = end - cnt;

    float4 acc = ((const float4*)(y + (size_t)d * NC))[lane];  // self loop
    for (int base = 0; base < cnt; base += 32) {
        int rem = cnt - base;
        int m = rem < 32 ? rem : 32;
        int sv = (lane < m) ? csr_src[start + base + lane] : NNODE; // zero row
        int mm = (m + 3) & ~3;
        for (int j = 0; j < mm; j += 4) {
            int s0 = __shfl(sv, j + 0, 32);
            int s1 = __shfl(sv, j + 1, 32);
            int s2 = __shfl(sv, j + 2, 32);
            int s3 = __shfl(sv, j + 3, 32);
            float4 v0 = ((const float4*)(y + (size_t)s0 * NC))[lane];
            float4 v1 = ((const float4*)(y + (size_t)s1 * NC))[lane];
            float4 v2 = ((const float4*)(y + (size_t)s2 * NC))[lane];
            float4 v3 = ((const float4*)(y + (size_t)s3 * NC))[lane];
            acc.x += v0.x + v1.x + v2.x + v3.x;
            acc.y += v0.y + v1.y + v2.y + v3.y;
            acc.z += v0.z + v1.z + v2.z + v3.z;
            acc.w += v0.w + v1.w + v2.w + v3.w;
        }
    }

    const float dv = dinv[d];
    float4 b  = ((const float4*)bias)[lane];
    float4 st = ((const float4*)(state + (size_t)d * NC))[lane];
    float4 r;
    r.x = fmaxf(acc.x * dv + b.x, 0.f) + st.x;
    r.y = fmaxf(acc.y * dv + b.y, 0.f) + st.y;
    r.z = fmaxf(acc.z * dv + b.z, 0.f) + st.z;
    r.w = fmaxf(acc.w * dv + b.w, 0.f) + st.w;
    ((float4*)(xout + (size_t)d * NC))[lane] = r;
}

// ---------------------------------------------------------------------------
// pairs kernel, scalar-pipe weights: 1 pair per thread, NO LDS.
// All weight/bias accesses use thread-uniform indices on const __restrict__
// pointers (kernel writes only `out`) -> backend promotes them to s_load and
// the inner loop is pure v_fma_f32 with an SGPR multiplier.
// h2[32] in registers; #pragma unroll 2 on the k4 loop caps VGPR pressure.
// ---------------------------------------------------------------------------
__device__ __forceinline__ float softplusf(float z)
{
    return z > 0.f ? z + log1pf(expf(-z)) : log1pf(expf(z));
}

__global__ __launch_bounds__(256) void pairs_sgpr_kernel(
    const float* __restrict__ uv, const float* __restrict__ W2,
    const float* __restrict__ b1, const float* __restrict__ b2,
    const float* __restrict__ muW, const float* __restrict__ mu_b,
    const float* __restrict__ sigW, const float* __restrict__ sig_b,
    float* __restrict__ out)
{
    const int gid = blockIdx.x * 256 + threadIdx.x;   // 0 .. NPAIR-1
    const int b = gid / 196;
    const int p = gid - b * 196;
    const int i = p / 14;
    const int j = p - i * 14;

    const float* up = uv + (size_t)(b * ACT + i) * 64;
    const float* vp = uv + (size_t)(b * ACT + j) * 64 + 32;

    float h2[32];
#pragma unroll
    for (int l = 0; l < 32; ++l) h2[l] = b2[l];       // uniform -> s_load

#pragma unroll 2
    for (int k4 = 0; k4 < 8; ++k4) {
        float4 uu = ((const float4*)up)[k4];
        float4 vv = ((const float4*)vp)[k4];
#pragma unroll
        for (int kk = 0; kk < 4; ++kk) {
            float uvk = (kk == 0) ? uu.x + vv.x :
                        (kk == 1) ? uu.y + vv.y :
                        (kk == 2) ? uu.z + vv.z : uu.w + vv.w;
            float z = uvk + b1[k4 * 4 + kk];          // b1 uniform -> sgpr
            float h1k = z > 0.f ? z : 0.01f * z;
            const float* wrow = W2 + (k4 * 4 + kk) * 32;
#pragma unroll
            for (int l = 0; l < 32; ++l)
                h2[l] += h1k * wrow[l];               // s_load + v_fma (sgpr src)
        }
    }

    float mu_acc = mu_b[0] + 1e-10f;
    float sg = sig_b[0];
#pragma unroll
    for (int l = 0; l < 32; ++l) {
        float h = h2[l];
        h = h > 0.f ? h : 0.01f * h;
        mu_acc += h * muW[l];
        sg += h * sigW[l];
    }
    out[gid]         = softplusf(mu_acc);
    out[NPAIR + gid] = expf(fminf(fmaxf(sg, -20.f), 2.f));
}

// ---------------------------------------------------------------------------
// launch
// ---------------------------------------------------------------------------
extern "C" void kernel_launch(void* const* d_in, const int* in_sizes, int n_in,
                              void* d_out, int out_size, void* d_ws, size_t ws_size,
                              hipStream_t stream)
{
    const float* state  = (const float*)d_in[0];
    const float* conv_W = (const float*)d_in[1];
    const float* conv_b = (const float*)d_in[2];
    const float* lin1_W = (const float*)d_in[3];
    const float* lin1_b = (const float*)d_in[4];
    const float* lin2_W = (const float*)d_in[5];
    const float* lin2_b = (const float*)d_in[6];
    const float* mu_W   = (const float*)d_in[7];
    const float* mu_b   = (const float*)d_in[8];
    const float* sig_W  = (const float*)d_in[9];
    const float* sig_b  = (const float*)d_in[10];
    const int*   eidx   = (const int*)d_in[11];
    const int* e_src = eidx;
    const int* e_dst = eidx + NEDGE;

    float* out = (float*)d_out;

    // workspace layout (floats)
    float* ws = (float*)d_ws;
    float* y     = ws;                               // (N+1)*128; row N = zeros
    float* x     = y + (size_t)(NNODE + 1) * 128;    // N*128
    float* dinv  = x + (size_t)NNODE * 128;          // N
    int*   deg   = (int*)(dinv + NNODE);             // N
    int*   cursor= deg + NNODE;                      // N
    int*   csrs  = cursor + NNODE;                   // E
    float* Wp    = (float*)(csrs + NEDGE);           // 128*64
    float* uvb   = Wp + 128 * 64;                    // uv [N x 64]

    // init: deg=0, y dummy row=0, Wp packed  (one kernel, replaces 2 memsets)
    init_misc<<<(NNODE + 255) / 256, 256, 0, stream>>>(
        deg, y + (size_t)NNODE * 128, lin1_W, Wp);

    // CSR build
    deg_count<<<NEDGE / 256, 256, 0, stream>>>(e_dst, deg);
    scan_dinv<<<1, 1024, 0, stream>>>(deg, cursor, dinv);
    csr_fill<<<NEDGE / 256, 256, 0, stream>>>(e_src, e_dst, cursor, csrs);

    // y = (state @ conv_W) * dinv[row]
    gemm_k128<<<dim3(NNODE / 64, 2), 256, 0, stream>>>(state, conv_W, y, 128, dinv);

    // x = relu(dinv*(y_self + sum y[src]) + b) + state
    gather_agg<<<(NNODE * 32) / 256, 256, 0, stream>>>(
        csrs, cursor, deg, y, dinv, conv_b, state, x);

    // uv = x @ [W1_top | W1_bot]
    gemm_k128<<<dim3(NNODE / 64, 1), 256, 0, stream>>>(x, Wp, uvb, 64, nullptr);

    // pairs -> output (1 pair per thread, scalar-pipe weights)
    pairs_sgpr_kernel<<<NPAIR / 256, 256, 0, stream>>>(
        uvb, lin2_W, lin1_b, lin2_b, mu_W, mu_b, sig_W, sig_b, out);
}